// Round 2
// baseline (9304.820 us; speedup 1.0000x reference)
//
#include <hip/hip_runtime.h>
#include <hip/hip_bf16.h>

typedef unsigned short u16;
typedef unsigned int   u32;

#define NN 100000
#define EE 800000

__device__ __forceinline__ float b2f(u16 u) {
    u32 x = ((u32)u) << 16;
    return __uint_as_float(x);
}

template<int BF16>
__device__ __forceinline__ float ldf(const void* p, long idx) {
    if (BF16) return b2f(((const u16*)p)[idx]);
    return ((const float*)p)[idx];
}

__device__ __forceinline__ float bcastf(float v, int l) {
    return __uint_as_float(__builtin_amdgcn_readlane(__float_as_uint(v), l));
}

// dtype detector: bf16 stream => ~all u16 words have plausible bf16 exponent;
// fp32 stream => only high halves do (~58%). Threshold 200/256.
__global__ void k_detect(const void* __restrict__ pos, int* __restrict__ flag) {
    if (threadIdx.x == 0 && blockIdx.x == 0) {
        const u16* p = (const u16*)pos;
        int cnt = 0;
        for (int i = 0; i < 256; ++i) {
            int e = (p[i] >> 7) & 0xFF;
            if (e >= 100 && e <= 140) cnt++;
        }
        flag[0] = (cnt >= 200) ? 1 : 0;
    }
}

template<int BF16>
__device__ __forceinline__ void embed_body(const void* pos, const int* z,
                                           const void* emb, float* x) {
    int gid = blockIdx.x * 256 + threadIdx.x;
    int i = gid >> 6, f = gid & 63;
    float v;
    if (f < 3) v = ldf<BF16>(pos, (long)i * 3 + f);
    else       v = ldf<BF16>(emb, (long)z[i] * 61 + (f - 3));
    x[gid] = v;
}
__global__ __launch_bounds__(256) void k_embed(const void* pos, const int* z,
                                               const void* emb, float* x,
                                               const int* flag) {
    if (flag[0]) embed_body<1>(pos, z, emb, x);
    else         embed_body<0>(pos, z, emb, x);
}

template<int BF16>
__device__ __forceinline__ void proj_body(const float* x, float* out,
                                          const void* W, int relu_in) {
    int node = blockIdx.x * 4 + (threadIdx.x >> 6);
    int j = threadIdx.x & 63;
    float v = x[node * 64 + j];
    if (relu_in) v = fmaxf(v, 0.f);
    float acc = 0.f;
#pragma unroll
    for (int k = 0; k < 64; ++k)
        acc += bcastf(v, k) * ldf<BF16>(W, k * 64 + j);
    out[node * 64 + j] = acc;
}
__global__ __launch_bounds__(256) void k_proj(const float* x, float* out,
                                              const void* W, int relu_in,
                                              const int* flag) {
    if (flag[0]) proj_body<1>(x, out, W, relu_in);
    else         proj_body<0>(x, out, W, relu_in);
}

template<int BF16>
__device__ __forceinline__ void d2_body(const void* pos, const int* src,
                                        const int* dst, float* d2) {
    int e = blockIdx.x * 256 + threadIdx.x;
    if (e >= EE) return;
    int s = src[e], d = dst[e];
    float dx = ldf<BF16>(pos, (long)s * 3 + 0) - ldf<BF16>(pos, (long)d * 3 + 0);
    float dy = ldf<BF16>(pos, (long)s * 3 + 1) - ldf<BF16>(pos, (long)d * 3 + 1);
    float dz = ldf<BF16>(pos, (long)s * 3 + 2) - ldf<BF16>(pos, (long)d * 3 + 2);
    d2[e] = dx * dx + dy * dy + dz * dz;
}
__global__ __launch_bounds__(256) void k_d2(const void* pos, const int* src,
                                            const int* dst, float* d2,
                                            const int* flag) {
    if (flag[0]) d2_body<1>(pos, src, dst, d2);
    else         d2_body<0>(pos, src, dst, d2);
}

__global__ __launch_bounds__(256) void k_deg(const int* __restrict__ dst,
                                             int* __restrict__ deg) {
    int e = blockIdx.x * 256 + threadIdx.x;
    if (e < EE) atomicAdd(&deg[dst[e]], 1);
}

__global__ __launch_bounds__(1024) void k_scan(const int* __restrict__ deg,
                                               int* __restrict__ rowptr) {
    __shared__ int s[1024];
    int carry = 0;
    for (int base = 0; base < NN; base += 1024) {
        int i = base + (int)threadIdx.x;
        int v = (i < NN) ? deg[i] : 0;
        s[threadIdx.x] = v;
        __syncthreads();
        for (int off = 1; off < 1024; off <<= 1) {
            int t = (threadIdx.x >= (unsigned)off) ? s[threadIdx.x - off] : 0;
            __syncthreads();
            s[threadIdx.x] += t;
            __syncthreads();
        }
        int incl = s[threadIdx.x];
        if (i < NN) rowptr[i] = carry + incl - v;
        carry += s[1023];
        __syncthreads();
    }
    if (threadIdx.x == 0) rowptr[NN] = carry;
}

__global__ __launch_bounds__(256) void k_scatter(const int* __restrict__ dst,
                                                 int* __restrict__ cursor,
                                                 int* __restrict__ eidx) {
    int e = blockIdx.x * 256 + threadIdx.x;
    if (e < EE) {
        int p = atomicAdd(&cursor[dst[e]], 1);
        eidx[p] = e;
    }
}

// weights passed as base + ELEMENT offset; dtype applied inside ldf.
template<int BF16>
__device__ __forceinline__ void edges_body(const float* h, float* agg,
                                           const float* d2, const int* rowptr,
                                           const int* eidx, const int* src,
                                           const void* W1b, long oW1,
                                           const void* b1b, long ob1,
                                           const void* W2b, long oW2,
                                           const void* b2b, long ob2) {
    int node = blockIdx.x * 4 + (threadIdx.x >> 6);
    int j = threadIdx.x & 63;
    if (node >= NN) return;
    float hj = h[node * 64 + j];
    int e0 = rowptr[node], e1 = rowptr[node + 1];
    float acc = 0.f;
    float b1j = ldf<BF16>(b1b, ob1 + j);
    float b2j = ldf<BF16>(b2b, ob2 + j);
    for (int t = e0; t < e1; ++t) {
        int e = eidx[t];
        int s = src[e];
        float hs = h[s * 64 + j];
        float dd = d2[e];
        float a = b1j;
#pragma unroll
        for (int k = 0; k < 64; ++k)
            a += bcastf(hs, k) * ldf<BF16>(W1b, oW1 + k * 64 + j);
#pragma unroll
        for (int k = 0; k < 64; ++k)
            a += bcastf(hj, k) * ldf<BF16>(W1b, oW1 + (64 + k) * 64 + j);
        a += dd * ldf<BF16>(W1b, oW1 + 128 * 64 + j);
        float hid = fmaxf(a, 0.f);
        float m = b2j;
#pragma unroll
        for (int k = 0; k < 64; ++k)
            m += bcastf(hid, k) * ldf<BF16>(W2b, oW2 + k * 64 + j);
        acc += m;
    }
    agg[node * 64 + j] = acc;
}
__global__ __launch_bounds__(256) void k_edges(const float* h, float* agg,
                                               const float* d2, const int* rowptr,
                                               const int* eidx, const int* src,
                                               const void* W1b, long oW1,
                                               const void* b1b, long ob1,
                                               const void* W2b, long oW2,
                                               const void* b2b, long ob2,
                                               const int* flag) {
    if (flag[0]) edges_body<1>(h, agg, d2, rowptr, eidx, src, W1b, oW1, b1b, ob1, W2b, oW2, b2b, ob2);
    else         edges_body<0>(h, agg, d2, rowptr, eidx, src, W1b, oW1, b1b, ob1, W2b, oW2, b2b, ob2);
}

template<int BF16>
__device__ __forceinline__ void node_body(float* h, const float* agg,
                                          const void* W3b, long oW3,
                                          const void* b3b, long ob3) {
    int node = blockIdx.x * 4 + (threadIdx.x >> 6);
    int j = threadIdx.x & 63;
    float hj = h[node * 64 + j];
    float aj = agg[node * 64 + j];
    float u = ldf<BF16>(b3b, ob3 + j);
#pragma unroll
    for (int k = 0; k < 64; ++k)
        u += bcastf(hj, k) * ldf<BF16>(W3b, oW3 + k * 64 + j);
#pragma unroll
    for (int k = 0; k < 64; ++k)
        u += bcastf(aj, k) * ldf<BF16>(W3b, oW3 + (64 + k) * 64 + j);
    h[node * 64 + j] = hj + fmaxf(u, 0.f);
}
__global__ __launch_bounds__(256) void k_node(float* h, const float* agg,
                                              const void* W3b, long oW3,
                                              const void* b3b, long ob3,
                                              const int* flag) {
    if (flag[0]) node_body<1>(h, agg, W3b, oW3, b3b, ob3);
    else         node_body<0>(h, agg, W3b, oW3, b3b, ob3);
}

__global__ __launch_bounds__(256) void k_count(const int* __restrict__ batch,
                                               float* __restrict__ cnt) {
    int i = blockIdx.x * 256 + threadIdx.x;
    if (i < NN) atomicAdd(&cnt[batch[i]], 1.f);
}

template<int BF16>
__device__ __forceinline__ void final_body(const float* h, const int* batch,
                                           const void* Wlin, const void* blin,
                                           float* pool) {
    int node = blockIdx.x * 4 + (threadIdx.x >> 6);
    int j = threadIdx.x & 63;
    int jj = j & 31;
    float v = fmaxf(h[node * 64 + j], 0.f);
    float acc = ldf<BF16>(blin, jj);
#pragma unroll
    for (int k = 0; k < 64; ++k)
        acc += bcastf(v, k) * ldf<BF16>(Wlin, k * 32 + jj);
    if (j < 32) atomicAdd(&pool[batch[node] * 32 + jj], acc);
}
__global__ __launch_bounds__(256) void k_final(const float* h, const int* batch,
                                               const void* Wlin, const void* blin,
                                               float* pool, const int* flag) {
    if (flag[0]) final_body<1>(h, batch, Wlin, blin, pool);
    else         final_body<0>(h, batch, Wlin, blin, pool);
}

__global__ __launch_bounds__(256) void k_out(const float* __restrict__ pool,
                                             const float* __restrict__ cnt,
                                             void* __restrict__ out,
                                             const int* __restrict__ flag) {
    int idx = blockIdx.x * 256 + threadIdx.x;
    if (idx >= 64 * 32) return;
    int g = idx >> 5;
    float c = fmaxf(cnt[g], 1.f);
    float v = pool[idx] / c;
    if (flag[0]) ((__hip_bfloat16*)out)[idx] = __float2bfloat16(v);
    else         ((float*)out)[idx] = v;
}

extern "C" void kernel_launch(void* const* d_in, const int* in_sizes, int n_in,
                              void* d_out, int out_size, void* d_ws, size_t ws_size,
                              hipStream_t stream) {
    const void* pos    = d_in[0];
    const int*  z      = (const int*)d_in[1];
    const int*  ei     = (const int*)d_in[2];
    const int*  batch  = (const int*)d_in[3];
    const void* emb    = d_in[4];
    const void* t1_Win = d_in[5];
    const void* t1_W1  = d_in[6];
    const void* t1_b1  = d_in[7];
    const void* t1_W2  = d_in[8];
    const void* t1_b2  = d_in[9];
    const void* t1_W3  = d_in[10];
    const void* t1_b3  = d_in[11];
    const void* t2_Win = d_in[12];
    const void* t2_W1  = d_in[13];
    const void* t2_b1  = d_in[14];
    const void* t2_W2  = d_in[15];
    const void* t2_b2  = d_in[16];
    const void* t2_W3  = d_in[17];
    const void* t2_b3  = d_in[18];
    const void* Wlin   = d_in[19];
    const void* blin   = d_in[20];

    const int* srcI = ei;
    const int* dstI = ei + EE;

    char* ws = (char*)d_ws;
    size_t off = 0;
    auto alloc = [&](size_t bytes) -> void* {
        void* p = ws + off;
        off += (bytes + 255) / 256 * 256;
        return p;
    };
    float* bufA   = (float*)alloc((size_t)NN * 64 * 4);
    float* bufB   = (float*)alloc((size_t)NN * 64 * 4);
    float* d2     = (float*)alloc((size_t)EE * 4);
    int*   rowptr = (int*)alloc((size_t)(NN + 1) * 4);
    int*   cursor = (int*)alloc((size_t)NN * 4);
    int*   eidx   = (int*)alloc((size_t)EE * 4);
    float* pool   = (float*)alloc(64 * 32 * 4);
    float* cnt    = (float*)alloc(64 * 4);
    int*   flag   = (int*)alloc(256);

    k_detect<<<1, 64, 0, stream>>>(pos, flag);

    k_embed<<<NN * 64 / 256, 256, 0, stream>>>(pos, z, emb, bufB, flag);
    k_proj<<<NN / 4, 256, 0, stream>>>(bufB, bufA, t1_Win, 0, flag);
    k_d2<<<(EE + 255) / 256, 256, 0, stream>>>(pos, srcI, dstI, d2, flag);

    hipMemsetAsync(cursor, 0, (size_t)NN * 4, stream);
    k_deg<<<(EE + 255) / 256, 256, 0, stream>>>(dstI, cursor);
    k_scan<<<1, 1024, 0, stream>>>(cursor, rowptr);
    hipMemcpyAsync(cursor, rowptr, (size_t)NN * 4, hipMemcpyDeviceToDevice, stream);
    k_scatter<<<(EE + 255) / 256, 256, 0, stream>>>(dstI, cursor, eidx);

    for (int l = 0; l < 4; ++l) {
        k_edges<<<NN / 4, 256, 0, stream>>>(bufA, bufB, d2, rowptr, eidx, srcI,
                                            t1_W1, (long)l * 129 * 64,
                                            t1_b1, (long)l * 64,
                                            t1_W2, (long)l * 64 * 64,
                                            t1_b2, (long)l * 64, flag);
        k_node<<<NN / 4, 256, 0, stream>>>(bufA, bufB,
                                           t1_W3, (long)l * 128 * 64,
                                           t1_b3, (long)l * 64, flag);
    }

    k_proj<<<NN / 4, 256, 0, stream>>>(bufA, bufB, t2_Win, 1, flag);
    for (int l = 0; l < 4; ++l) {
        k_edges<<<NN / 4, 256, 0, stream>>>(bufB, bufA, d2, rowptr, eidx, srcI,
                                            t2_W1, (long)l * 129 * 64,
                                            t2_b1, (long)l * 64,
                                            t2_W2, (long)l * 64 * 64,
                                            t2_b2, (long)l * 64, flag);
        k_node<<<NN / 4, 256, 0, stream>>>(bufB, bufA,
                                           t2_W3, (long)l * 128 * 64,
                                           t2_b3, (long)l * 64, flag);
    }

    hipMemsetAsync(pool, 0, 64 * 32 * 4, stream);
    hipMemsetAsync(cnt, 0, 64 * 4, stream);
    k_count<<<(NN + 255) / 256, 256, 0, stream>>>(batch, cnt);
    k_final<<<NN / 4, 256, 0, stream>>>(bufB, batch, Wlin, blin, pool, flag);
    k_out<<<8, 256, 0, stream>>>(pool, cnt, d_out, flag);
}